// Round 3
// baseline (1675.538 us; speedup 1.0000x reference)
//
#include <hip/hip_runtime.h>
#include <hip/hip_bf16.h>
#include <cstdint>

#define NROWS 8192
#define DDIM  1024
#define QBLK  16
#define KVT   128
#define DC    64
#define NW    8
#define NITER (NROWS / KVT)
#define NDC   (DDIM / DC)
#define LOG2E 1.44269504088896340736f

typedef __attribute__((ext_vector_type(4))) float f32x4;
typedef __attribute__((ext_vector_type(8))) short bf16x8;
typedef unsigned short u16;

__device__ __forceinline__ u16 f2bf(float f) {
  uint32_t u = __builtin_bit_cast(uint32_t, f);
  uint32_t r = u + 0x7FFFu + ((u >> 16) & 1u);  // round-to-nearest-even
  return (u16)(r >> 16);
}

// Prep: xbf = bf16(x) row-major [N][D]; xbfT = bf16(x)^T [D][N]
__global__ __launch_bounds__(256) void prep_kernel(const float* __restrict__ x,
                                                   u16* __restrict__ xbf,
                                                   u16* __restrict__ xbfT) {
  __shared__ __align__(16) u16 T[64][72];
  const int t = threadIdx.x;
  const int n0 = blockIdx.x * 64;
  const int d0 = blockIdx.y * 64;
#pragma unroll
  for (int rr = 0; rr < 4; ++rr) {
    const int row = (t >> 4) + rr * 16;
    const int c4 = (t & 15) * 4;
    const float4 v = *reinterpret_cast<const float4*>(&x[(size_t)(n0 + row) * DDIM + d0 + c4]);
    ushort4 b;
    b.x = f2bf(v.x); b.y = f2bf(v.y); b.z = f2bf(v.z); b.w = f2bf(v.w);
    *reinterpret_cast<ushort4*>(&xbf[(size_t)(n0 + row) * DDIM + d0 + c4]) = b;
    *reinterpret_cast<ushort4*>(&T[row][c4]) = b;
  }
  __syncthreads();
#pragma unroll
  for (int rr = 0; rr < 4; ++rr) {
    const int drow = (t >> 4) + rr * 16;
    const int nc = (t & 15) * 4;
    ushort4 o;
    o.x = T[nc + 0][drow]; o.y = T[nc + 1][drow];
    o.z = T[nc + 2][drow]; o.w = T[nc + 3][drow];
    *reinterpret_cast<ushort4*>(&xbfT[(size_t)(d0 + drow) * NROWS + n0 + nc]) = o;
  }
}

// Flash attention: one block per 16 q-rows, 8 waves -> grid 512 = 2 blocks/CU.
// Wave w: S-phase kv slice [w*16, w*16+16); PV-phase O columns [w*128, w*128+128).
__global__ __launch_bounds__(512, 4) void attn_kernel(const u16* __restrict__ xbf,
                                                      const u16* __restrict__ xbfT,
                                                      float* __restrict__ out) {
  // Q resident in LDS for the whole block (loaded once; no per-chunk restaging).
  __shared__ __align__(16) u16 Qf[QBLK][DDIM + 8];   // 33,024 B (stride 2064B ≡ 4 banks)
  __shared__ __align__(16) u16 Ks[2][KVT][DC + 8];   // 36,864 B (stride 144B ≡ 4 banks)
  __shared__ __align__(16) u16 Ps[QBLK][KVT + 8];    //  4,352 B
  __shared__ float smax[NW][QBLK];
  __shared__ float ssum[NW][QBLK];

  const int tid = threadIdx.x;
  const int w = tid >> 6;
  const int lane = tid & 63;
  const int g = lane >> 4;
  const int ln16 = lane & 15;
  const int q0 = blockIdx.x * QBLK;

  // ---- Q prologue: 16 rows x 1024 cols, each thread 4x int4 --------------
  {
    const int qr = tid >> 5;            // 0..15
    const int qc0 = (tid & 31) * 32;    // 0..992
#pragma unroll
    for (int i = 0; i < 4; ++i) {
      const int4 v = *reinterpret_cast<const int4*>(&xbf[(size_t)(q0 + qr) * DDIM + qc0 + i * 8]);
      *reinterpret_cast<int4*>(&Qf[qr][qc0 + i * 8]) = v;
    }
  }

  // K staging map: 128 rows x 64 cols per chunk
  const int kr = tid >> 2, kc = (tid & 3) * 16;
  int4 rk0, rk1;
  auto load_chunk = [&](int t_, int dc_) {
    const size_t ko = (size_t)(t_ * KVT + kr) * DDIM + dc_ * DC + kc;
    rk0 = *reinterpret_cast<const int4*>(&xbf[ko]);
    rk1 = *reinterpret_cast<const int4*>(&xbf[ko + 8]);
  };
  auto write_chunk = [&](int buf) {
    *reinterpret_cast<int4*>(&Ks[buf][kr][kc]) = rk0;
    *reinterpret_cast<int4*>(&Ks[buf][kr][kc + 8]) = rk1;
  };

  f32x4 oacc[8];
#pragma unroll
  for (int c = 0; c < 8; ++c) oacc[c] = (f32x4){0.f, 0.f, 0.f, 0.f};
  float m_run = -INFINITY, l_run = 0.0f;

  load_chunk(0, 0);

  for (int t = 0; t < NITER; ++t) {
    // ---------------- S = Q K^T over D (chunked, double-buffered K) --------
    f32x4 sacc = {0.f, 0.f, 0.f, 0.f};
    for (int dc = 0; dc < NDC; ++dc) {
      const int buf = dc & 1;
      write_chunk(buf);
      if (dc + 1 < NDC) load_chunk(t, dc + 1);
      else if (t + 1 < NITER) load_chunk(t + 1, 0);
      __syncthreads();   // also covers Q prologue visibility at t==0,dc==0
#pragma unroll
      for (int kk = 0; kk < 2; ++kk) {
        bf16x8 a = *reinterpret_cast<const bf16x8*>(&Qf[ln16][dc * DC + kk * 32 + g * 8]);
        bf16x8 b = *reinterpret_cast<const bf16x8*>(&Ks[buf][w * 16 + ln16][kk * 32 + g * 8]);
        sacc = __builtin_amdgcn_mfma_f32_16x16x32_bf16(a, b, sacc, 0, 0, 0);
      }
    }
    // S frag: row q = g*4+r, col kv = w*16 + ln16

    // ---------------- online softmax (cross-wave via LDS stats) ------------
    float rmx[4];
#pragma unroll
    for (int r = 0; r < 4; ++r) {
      float v = sacc[r];
      v = fmaxf(v, __shfl_xor(v, 1, 16));
      v = fmaxf(v, __shfl_xor(v, 2, 16));
      v = fmaxf(v, __shfl_xor(v, 4, 16));
      v = fmaxf(v, __shfl_xor(v, 8, 16));
      rmx[r] = v;
    }
    if (ln16 == 0) {
#pragma unroll
      for (int r = 0; r < 4; ++r) smax[w][g * 4 + r] = rmx[r];
    }
    __syncthreads();
    float tm = smax[0][ln16];
#pragma unroll
    for (int wv = 1; wv < NW; ++wv) tm = fmaxf(tm, smax[wv][ln16]);
    const float mnew = fmaxf(m_run, tm);
    const float alpha = exp2f((m_run - mnew) * LOG2E);
    m_run = mnew;

    float mrow[4], arow[4];
#pragma unroll
    for (int r = 0; r < 4; ++r) {
      mrow[r] = __shfl(mnew, g * 4 + r);
      arow[r] = __shfl(alpha, g * 4 + r);
    }

    float prb[4], rs[4];
#pragma unroll
    for (int r = 0; r < 4; ++r) {
      const float p = exp2f((sacc[r] - mrow[r]) * LOG2E);
      prb[r] = p;
      float s = p;
      s += __shfl_xor(s, 1, 16);
      s += __shfl_xor(s, 2, 16);
      s += __shfl_xor(s, 4, 16);
      s += __shfl_xor(s, 8, 16);
      rs[r] = s;
    }
    if (ln16 == 0) {
#pragma unroll
      for (int r = 0; r < 4; ++r) ssum[w][g * 4 + r] = rs[r];
    }
#pragma unroll
    for (int r = 0; r < 4; ++r)
      Ps[g * 4 + r][w * 16 + ln16] = f2bf(prb[r]);
    __syncthreads();

    float ts = ssum[0][ln16];
#pragma unroll
    for (int wv = 1; wv < NW; ++wv) ts += ssum[wv][ln16];
    l_run = l_run * alpha + ts;

#pragma unroll
    for (int cf = 0; cf < 8; ++cf)
#pragma unroll
      for (int r = 0; r < 4; ++r) oacc[cf][r] *= arow[r];

    // ---------------- O += P V  (V frags gathered from xbfT, L2-hot) -------
    const int kvb = t * KVT;
#pragma unroll
    for (int kk = 0; kk < 4; ++kk) {
      // issue all 8 V loads first -> one vmcnt drain, then MFMA back-to-back
      int4 vv[8];
#pragma unroll
      for (int cf = 0; cf < 8; ++cf) {
        const int c = w * 128 + cf * 16 + ln16;
        vv[cf] = *reinterpret_cast<const int4*>(
            &xbfT[(size_t)c * NROWS + kvb + kk * 32 + g * 8]);
      }
      const bf16x8 pa = *reinterpret_cast<const bf16x8*>(&Ps[ln16][kk * 32 + g * 8]);
      __builtin_amdgcn_s_setprio(1);
#pragma unroll
      for (int cf = 0; cf < 8; ++cf) {
        oacc[cf] = __builtin_amdgcn_mfma_f32_16x16x32_bf16(
            pa, __builtin_bit_cast(bf16x8, vv[cf]), oacc[cf], 0, 0, 0);
      }
      __builtin_amdgcn_s_setprio(0);
    }
  }

  // ---------------- epilogue: out = O / l ---------------------------------
  const float rinv = 1.0f / l_run;
  float rrow[4];
#pragma unroll
  for (int r = 0; r < 4; ++r) rrow[r] = __shfl(rinv, g * 4 + r);
#pragma unroll
  for (int cf = 0; cf < 8; ++cf)
#pragma unroll
    for (int r = 0; r < 4; ++r) {
      const int row = q0 + g * 4 + r;
      const int c = w * 128 + cf * 16 + ln16;
      out[(size_t)row * DDIM + c] = oacc[cf][r] * rrow[r];
    }
}

extern "C" void kernel_launch(void* const* d_in, const int* in_sizes, int n_in,
                              void* d_out, int out_size, void* d_ws, size_t ws_size,
                              hipStream_t stream) {
  const float* x = (const float*)d_in[0];
  u16* xbf  = (u16*)d_ws;                        // 16 MB
  u16* xbfT = xbf + (size_t)NROWS * DDIM;        // 16 MB
  float* out = (float*)d_out;

  hipLaunchKernelGGL(prep_kernel, dim3(NROWS / 64, DDIM / 64), dim3(256), 0, stream,
                     x, xbf, xbfT);
  hipLaunchKernelGGL(attn_kernel, dim3(NROWS / QBLK), dim3(512), 0, stream,
                     xbf, xbfT, out);
}

// Round 8
// 1059.712 us; speedup vs baseline: 1.5811x; 1.5811x over previous
//
#include <hip/hip_runtime.h>
#include <hip/hip_bf16.h>
#include <cstdint>

#define NROWS 8192
#define DDIM  1024
#define QBLK  32
#define KVT   256
#define NW    8
#define NITER (NROWS / KVT)   // 32 kv tiles
#define KS_S  (DDIM / 32)     // 32 k-steps in S phase
#define KS_PV (KVT / 32)      // 8 k-steps in PV phase
#define LOG2E 1.44269504088896340736f

typedef __attribute__((ext_vector_type(4))) float f32x4;
typedef __attribute__((ext_vector_type(8))) short bf16x8;
typedef unsigned short u16;

__device__ __forceinline__ u16 f2bf(float f) {
  uint32_t u = __builtin_bit_cast(uint32_t, f);
  uint32_t r = u + 0x7FFFu + ((u >> 16) & 1u);  // round-to-nearest-even
  return (u16)(r >> 16);
}
__device__ __forceinline__ bf16x8 asbf(int4 v) { return __builtin_bit_cast(bf16x8, v); }

// Prep: xbf = bf16(x) row-major [N][D]; xbfT = bf16(x)^T [D][N]
__global__ __launch_bounds__(256) void prep_kernel(const float* __restrict__ x,
                                                   u16* __restrict__ xbf,
                                                   u16* __restrict__ xbfT) {
  __shared__ __align__(16) u16 T[64][72];
  const int t = threadIdx.x;
  const int n0 = blockIdx.x * 64;
  const int d0 = blockIdx.y * 64;
#pragma unroll
  for (int rr = 0; rr < 4; ++rr) {
    const int row = (t >> 4) + rr * 16;
    const int c4 = (t & 15) * 4;
    const float4 v = *reinterpret_cast<const float4*>(&x[(size_t)(n0 + row) * DDIM + d0 + c4]);
    ushort4 b;
    b.x = f2bf(v.x); b.y = f2bf(v.y); b.z = f2bf(v.z); b.w = f2bf(v.w);
    *reinterpret_cast<ushort4*>(&xbf[(size_t)(n0 + row) * DDIM + d0 + c4]) = b;
    *reinterpret_cast<ushort4*>(&T[row][c4]) = b;
  }
  __syncthreads();
#pragma unroll
  for (int rr = 0; rr < 4; ++rr) {
    const int drow = (t >> 4) + rr * 16;
    const int nc = (t & 15) * 4;
    ushort4 o;
    o.x = T[nc + 0][drow]; o.y = T[nc + 1][drow];
    o.z = T[nc + 2][drow]; o.w = T[nc + 3][drow];
    *reinterpret_cast<ushort4*>(&xbfT[(size_t)(d0 + drow) * NROWS + n0 + nc]) = o;
  }
}

// Flash attention, barrier-minimal: grid 256 (1 block/CU), 8 waves.
// Per KV tile (256 rows): wave w owns kv slice [w*32,(w+1)*32) for S (K streamed
// from global via prefetch ring, NO LDS staging, NO barriers), and O columns
// [w*128,(w+1)*128) for PV (V streamed from xbfT). Exactly 2 barriers/tile.
__global__ __launch_bounds__(512, 2) void attn_kernel(const u16* __restrict__ xbf,
                                                      const u16* __restrict__ xbfT,
                                                      float* __restrict__ out) {
  __shared__ __align__(16) u16 Qf[QBLK][DDIM + 8];  // resident Q, 66 KB (stride 2064B)
  __shared__ __align__(16) u16 Ps[QBLK][KVT + 8];   // P exchange, 16.9 KB (stride 528B)
  __shared__ float smax[NW][QBLK];
  __shared__ float ssum[NW][QBLK];

  const int tid = threadIdx.x;
  const int w = tid >> 6;
  const int lane = tid & 63;
  const int g = lane >> 4;
  const int ln16 = lane & 15;
  const int j = lane & 31;            // stat row owned by this lane
  const int q0 = blockIdx.x * QBLK;

  // ---- Q prologue: 32 x 1024, each thread 8 x int4 (128B) -----------------
  {
    const int qr = tid >> 4;           // 0..31
    const int qc0 = (tid & 15) * 64;   // 0..960
#pragma unroll
    for (int i = 0; i < 8; ++i) {
      const int4 v = *reinterpret_cast<const int4*>(&xbf[(size_t)(q0 + qr) * DDIM + qc0 + i * 8]);
      *reinterpret_cast<int4*>(&Qf[qr][qc0 + i * 8]) = v;
    }
  }
  __syncthreads();

  f32x4 oacc[2][8];
#pragma unroll
  for (int qf = 0; qf < 2; ++qf)
#pragma unroll
    for (int c = 0; c < 8; ++c) oacc[qf][c] = (f32x4){0.f, 0.f, 0.f, 0.f};
  float m_run = -INFINITY, l_run = 0.0f;

  for (int t = 0; t < NITER; ++t) {
    const int kvb = t * KVT;

    // ================= S = Q K^T : barrier-free per-wave K stream ==========
    const u16* kbase = xbf + (size_t)(kvb + w * 32) * DDIM + g * 8;
    f32x4 sacc[2][2] = {{{0.f,0.f,0.f,0.f},{0.f,0.f,0.f,0.f}},
                        {{0.f,0.f,0.f,0.f},{0.f,0.f,0.f,0.f}}};
    int4 kb[4][2];  // distance-3 prefetch ring: 6 KB in flight per wave
#pragma unroll
    for (int p = 0; p < 3; ++p) {
      kb[p][0] = *reinterpret_cast<const int4*>(kbase + (size_t)ln16 * DDIM + p * 32);
      kb[p][1] = *reinterpret_cast<const int4*>(kbase + (size_t)(16 + ln16) * DDIM + p * 32);
    }
#pragma unroll
    for (int ks = 0; ks < KS_S; ++ks) {
      if (ks + 3 < KS_S) {
        kb[(ks + 3) & 3][0] = *reinterpret_cast<const int4*>(kbase + (size_t)ln16 * DDIM + (ks + 3) * 32);
        kb[(ks + 3) & 3][1] = *reinterpret_cast<const int4*>(kbase + (size_t)(16 + ln16) * DDIM + (ks + 3) * 32);
      }
      const bf16x8 a0 = *reinterpret_cast<const bf16x8*>(&Qf[ln16][ks * 32 + g * 8]);
      const bf16x8 a1 = *reinterpret_cast<const bf16x8*>(&Qf[16 + ln16][ks * 32 + g * 8]);
      const bf16x8 b0 = asbf(kb[ks & 3][0]);
      const bf16x8 b1 = asbf(kb[ks & 3][1]);
      sacc[0][0] = __builtin_amdgcn_mfma_f32_16x16x32_bf16(a0, b0, sacc[0][0], 0, 0, 0);
      sacc[1][0] = __builtin_amdgcn_mfma_f32_16x16x32_bf16(a1, b0, sacc[1][0], 0, 0, 0);
      sacc[0][1] = __builtin_amdgcn_mfma_f32_16x16x32_bf16(a0, b1, sacc[0][1], 0, 0, 0);
      sacc[1][1] = __builtin_amdgcn_mfma_f32_16x16x32_bf16(a1, b1, sacc[1][1], 0, 0, 0);
    }
    // S frag: row q = qf*16 + g*4 + r, col kv = w*32 + kf*16 + ln16

    // ================= online softmax (2 barriers) =========================
    float rmx[2][4];
#pragma unroll
    for (int qf = 0; qf < 2; ++qf)
#pragma unroll
      for (int r = 0; r < 4; ++r) {
        float v = fmaxf(sacc[qf][0][r], sacc[qf][1][r]);
        v = fmaxf(v, __shfl_xor(v, 1, 16));
        v = fmaxf(v, __shfl_xor(v, 2, 16));
        v = fmaxf(v, __shfl_xor(v, 4, 16));
        v = fmaxf(v, __shfl_xor(v, 8, 16));
        rmx[qf][r] = v;
      }
    if (ln16 == 0) {
#pragma unroll
      for (int qf = 0; qf < 2; ++qf)
#pragma unroll
        for (int r = 0; r < 4; ++r) smax[w][qf * 16 + g * 4 + r] = rmx[qf][r];
    }
    __syncthreads();                                   // B1
    float tm = smax[0][j];
#pragma unroll
    for (int wv = 1; wv < NW; ++wv) tm = fmaxf(tm, smax[wv][j]);
    const float mnew = fmaxf(m_run, tm);
    const float alpha = exp2f((m_run - mnew) * LOG2E);
    m_run = mnew;

    float mrow[2][4], arow[2][4];
#pragma unroll
    for (int qf = 0; qf < 2; ++qf)
#pragma unroll
      for (int r = 0; r < 4; ++r) {
        mrow[qf][r] = __shfl(mnew, qf * 16 + g * 4 + r);
        arow[qf][r] = __shfl(alpha, qf * 16 + g * 4 + r);
      }

    float rs[2][4];
#pragma unroll
    for (int qf = 0; qf < 2; ++qf)
#pragma unroll
      for (int r = 0; r < 4; ++r) {
        const float p0 = exp2f((sacc[qf][0][r] - mrow[qf][r]) * LOG2E);
        const float p1 = exp2f((sacc[qf][1][r] - mrow[qf][r]) * LOG2E);
        Ps[qf * 16 + g * 4 + r][w * 32 + ln16]      = f2bf(p0);
        Ps[qf * 16 + g * 4 + r][w * 32 + 16 + ln16] = f2bf(p1);
        float s = p0 + p1;
        s += __shfl_xor(s, 1, 16);
        s += __shfl_xor(s, 2, 16);
        s += __shfl_xor(s, 4, 16);
        s += __shfl_xor(s, 8, 16);
        rs[qf][r] = s;
      }
    if (ln16 == 0) {
#pragma unroll
      for (int qf = 0; qf < 2; ++qf)
#pragma unroll
        for (int r = 0; r < 4; ++r) ssum[w][qf * 16 + g * 4 + r] = rs[qf][r];
    }
    __syncthreads();                                   // B2
    float ts = ssum[0][j];
#pragma unroll
    for (int wv = 1; wv < NW; ++wv) ts += ssum[wv][j];
    l_run = l_run * alpha + ts;

#pragma unroll
    for (int qf = 0; qf < 2; ++qf)
#pragma unroll
      for (int cf = 0; cf < 8; ++cf)
#pragma unroll
        for (int r = 0; r < 4; ++r) oacc[qf][cf][r] *= arow[qf][r];

    // ================= O += P V : per-wave V stream (no barriers) ==========
    const u16* vbase = xbfT + (size_t)(w * 128 + ln16) * NROWS + kvb + g * 8;
    int4 vv[2][8];  // distance-1 ring: 8 loads (8 KB) in flight per wave
#pragma unroll
    for (int cf = 0; cf < 8; ++cf)
      vv[0][cf] = *reinterpret_cast<const int4*>(vbase + (size_t)(cf * 16) * NROWS);
#pragma unroll
    for (int ks = 0; ks < KS_PV; ++ks) {
      const int cur = ks & 1;
      if (ks + 1 < KS_PV) {
#pragma unroll
        for (int cf = 0; cf < 8; ++cf)
          vv[cur ^ 1][cf] = *reinterpret_cast<const int4*>(
              vbase + (size_t)(cf * 16) * NROWS + (ks + 1) * 32);
      }
      const bf16x8 pa0 = *reinterpret_cast<const bf16x8*>(&Ps[ln16][ks * 32 + g * 8]);
      const bf16x8 pa1 = *reinterpret_cast<const bf16x8*>(&Ps[16 + ln16][ks * 32 + g * 8]);
      __builtin_amdgcn_s_setprio(1);
#pragma unroll
      for (int cf = 0; cf < 8; ++cf) {
        oacc[0][cf] = __builtin_amdgcn_mfma_f32_16x16x32_bf16(pa0, asbf(vv[cur][cf]), oacc[0][cf], 0, 0, 0);
        oacc[1][cf] = __builtin_amdgcn_mfma_f32_16x16x32_bf16(pa1, asbf(vv[cur][cf]), oacc[1][cf], 0, 0, 0);
      }
      __builtin_amdgcn_s_setprio(0);
    }
    // No barrier here: next S phase touches neither Ps nor stats before B1.
  }

  // ================= epilogue: out = O / l =================================
  const float rinv = 1.0f / l_run;
  float rrow[2][4];
#pragma unroll
  for (int qf = 0; qf < 2; ++qf)
#pragma unroll
    for (int r = 0; r < 4; ++r) rrow[qf][r] = __shfl(rinv, qf * 4 == 0 ? g * 4 + r : qf * 16 + g * 4 + r);
#pragma unroll
  for (int qf = 0; qf < 2; ++qf)
#pragma unroll
    for (int cf = 0; cf < 8; ++cf)
#pragma unroll
      for (int r = 0; r < 4; ++r) {
        const int row = q0 + qf * 16 + g * 4 + r;
        const int c = w * 128 + cf * 16 + ln16;
        out[(size_t)row * DDIM + c] = oacc[qf][cf][r] * rrow[qf][r];
      }
}

extern "C" void kernel_launch(void* const* d_in, const int* in_sizes, int n_in,
                              void* d_out, int out_size, void* d_ws, size_t ws_size,
                              hipStream_t stream) {
  const float* x = (const float*)d_in[0];
  u16* xbf  = (u16*)d_ws;                        // 16 MB
  u16* xbfT = xbf + (size_t)NROWS * DDIM;        // 16 MB
  float* out = (float*)d_out;

  hipLaunchKernelGGL(prep_kernel, dim3(NROWS / 64, DDIM / 64), dim3(256), 0, stream,
                     x, xbf, xbfT);
  hipLaunchKernelGGL(attn_kernel, dim3(NROWS / QBLK), dim3(512), 0, stream,
                     xbf, xbfT, out);
}

// Round 10
// 1059.493 us; speedup vs baseline: 1.5815x; 1.0002x over previous
//
#include <hip/hip_runtime.h>
#include <hip/hip_bf16.h>
#include <cstdint>

#define NROWS 8192
#define DDIM  1024
#define QBLK  32
#define KVT   256
#define NW    8
#define NITER (NROWS / KVT)   // 32 kv tiles
#define KS_S  (DDIM / 32)     // 32 k-steps in S phase
#define KS_PV (KVT / 32)      // 8 k-steps in PV phase
#define LOG2E 1.44269504088896340736f

typedef __attribute__((ext_vector_type(4))) float f32x4;
typedef __attribute__((ext_vector_type(8))) short bf16x8;
typedef unsigned short u16;

// Pinned 16B global load: volatile asm so the compiler cannot collapse the
// prefetch ring by shortening live ranges (round-8 diagnosis: VGPR=108 proved
// rings were serialized).
__device__ __forceinline__ int4 gload16(const u16* p) {
  int4 r;
  asm volatile("global_load_dwordx4 %0, %1, off" : "=v"(r) : "v"(p));
  return r;
}
// Counted vmem wait (T4): N = loads allowed to remain in flight. sched_barrier
// after it per guide rule #18 (compiler may hoist reg-only MFMA past asm waits).
#define VM_WAIT(N)                                     \
  do {                                                 \
    asm volatile("s_waitcnt vmcnt(" #N ")" ::: "memory"); \
    __builtin_amdgcn_sched_barrier(0);                 \
  } while (0)

__device__ __forceinline__ u16 f2bf(float f) {
  uint32_t u = __builtin_bit_cast(uint32_t, f);
  uint32_t r = u + 0x7FFFu + ((u >> 16) & 1u);  // round-to-nearest-even
  return (u16)(r >> 16);
}
__device__ __forceinline__ bf16x8 asbf(int4 v) { return __builtin_bit_cast(bf16x8, v); }

// Prep: xbf = bf16(x) row-major [N][D]; xbfT = bf16(x)^T [D][N]
__global__ __launch_bounds__(256) void prep_kernel(const float* __restrict__ x,
                                                   u16* __restrict__ xbf,
                                                   u16* __restrict__ xbfT) {
  __shared__ __align__(16) u16 T[64][72];
  const int t = threadIdx.x;
  const int n0 = blockIdx.x * 64;
  const int d0 = blockIdx.y * 64;
#pragma unroll
  for (int rr = 0; rr < 4; ++rr) {
    const int row = (t >> 4) + rr * 16;
    const int c4 = (t & 15) * 4;
    const float4 v = *reinterpret_cast<const float4*>(&x[(size_t)(n0 + row) * DDIM + d0 + c4]);
    ushort4 b;
    b.x = f2bf(v.x); b.y = f2bf(v.y); b.z = f2bf(v.z); b.w = f2bf(v.w);
    *reinterpret_cast<ushort4*>(&xbf[(size_t)(n0 + row) * DDIM + d0 + c4]) = b;
    *reinterpret_cast<ushort4*>(&T[row][c4]) = b;
  }
  __syncthreads();
#pragma unroll
  for (int rr = 0; rr < 4; ++rr) {
    const int drow = (t >> 4) + rr * 16;
    const int nc = (t & 15) * 4;
    ushort4 o;
    o.x = T[nc + 0][drow]; o.y = T[nc + 1][drow];
    o.z = T[nc + 2][drow]; o.w = T[nc + 3][drow];
    *reinterpret_cast<ushort4*>(&xbfT[(size_t)(d0 + drow) * NROWS + n0 + nc]) = o;
  }
}

// Flash attention: grid 256 (1 block/CU), 8 waves, 2 barriers/tile.
// K and V streamed per-wave from global through asm-pinned register rings with
// counted vmcnt waits; next-tile K prologue issued before PV (latency hides
// under PV MFMAs).
__global__ __launch_bounds__(512, 2) void attn_kernel(const u16* __restrict__ xbf,
                                                      const u16* __restrict__ xbfT,
                                                      float* __restrict__ out) {
  __shared__ __align__(16) u16 Qf[QBLK][DDIM + 8];  // resident Q, 66 KB
  __shared__ __align__(16) u16 Ps[QBLK][KVT + 8];   // P exchange, 16.9 KB
  __shared__ float smax[NW][QBLK];
  __shared__ float ssum[NW][QBLK];

  const int tid = threadIdx.x;
  const int w = tid >> 6;
  const int lane = tid & 63;
  const int g = lane >> 4;
  const int ln16 = lane & 15;
  const int j = lane & 31;
  const int q0 = blockIdx.x * QBLK;

  // ---- Q prologue: 32 x 1024, each thread 8 x int4 ------------------------
  {
    const int qr = tid >> 4;
    const int qc0 = (tid & 15) * 64;
#pragma unroll
    for (int i = 0; i < 8; ++i) {
      const int4 v = *reinterpret_cast<const int4*>(&xbf[(size_t)(q0 + qr) * DDIM + qc0 + i * 8]);
      *reinterpret_cast<int4*>(&Qf[qr][qc0 + i * 8]) = v;
    }
  }
  __syncthreads();

  f32x4 oacc[2][8];
#pragma unroll
  for (int qf = 0; qf < 2; ++qf)
#pragma unroll
    for (int c = 0; c < 8; ++c) oacc[qf][c] = (f32x4){0.f, 0.f, 0.f, 0.f};
  float m_run = -INFINITY, l_run = 0.0f;

  // K ring state: persists across tiles. Wave w streams kv rows
  // [t*KVT + w*32, +32): two row-pointers, distance-3 ring (6 loads in flight).
  const u16* kp0 = xbf + (size_t)(w * 32 + ln16) * DDIM + g * 8;
  const u16* kp1 = xbf + (size_t)(w * 32 + 16 + ln16) * DDIM + g * 8;
  int4 kb[4][2];
#pragma unroll
  for (int p = 0; p < 3; ++p) {
    kb[p][0] = gload16(kp0 + p * 32);
    kb[p][1] = gload16(kp1 + p * 32);
  }

  for (int t = 0; t < NITER; ++t) {
    const int kvb = t * KVT;

    // ================= S = Q K^T : asm-pinned K ring, no barriers ==========
    f32x4 sacc[2][2] = {{{0.f,0.f,0.f,0.f},{0.f,0.f,0.f,0.f}},
                        {{0.f,0.f,0.f,0.f},{0.f,0.f,0.f,0.f}}};
#pragma unroll
    for (int ks = 0; ks < KS_S; ++ks) {
      if (ks + 3 < KS_S) {
        kb[(ks + 3) & 3][0] = gload16(kp0 + (ks + 3) * 32);
        kb[(ks + 3) & 3][1] = gload16(kp1 + (ks + 3) * 32);
      }
      const bf16x8 a0 = *reinterpret_cast<const bf16x8*>(&Qf[ln16][ks * 32 + g * 8]);
      const bf16x8 a1 = *reinterpret_cast<const bf16x8*>(&Qf[16 + ln16][ks * 32 + g * 8]);
      // FIFO-exact waits: keep 6 in flight steady-state, 4/2/0 on the tail.
      if (ks < KS_S - 3)       VM_WAIT(6);
      else if (ks == KS_S - 3) VM_WAIT(4);
      else if (ks == KS_S - 2) VM_WAIT(2);
      else                     VM_WAIT(0);
      const bf16x8 b0 = asbf(kb[ks & 3][0]);
      const bf16x8 b1 = asbf(kb[ks & 3][1]);
      sacc[0][0] = __builtin_amdgcn_mfma_f32_16x16x32_bf16(a0, b0, sacc[0][0], 0, 0, 0);
      sacc[1][0] = __builtin_amdgcn_mfma_f32_16x16x32_bf16(a1, b0, sacc[1][0], 0, 0, 0);
      sacc[0][1] = __builtin_amdgcn_mfma_f32_16x16x32_bf16(a0, b1, sacc[0][1], 0, 0, 0);
      sacc[1][1] = __builtin_amdgcn_mfma_f32_16x16x32_bf16(a1, b1, sacc[1][1], 0, 0, 0);
    }

    // ================= online softmax (2 barriers) =========================
    float rmx[2][4];
#pragma unroll
    for (int qf = 0; qf < 2; ++qf)
#pragma unroll
      for (int r = 0; r < 4; ++r) {
        float v = fmaxf(sacc[qf][0][r], sacc[qf][1][r]);
        v = fmaxf(v, __shfl_xor(v, 1, 16));
        v = fmaxf(v, __shfl_xor(v, 2, 16));
        v = fmaxf(v, __shfl_xor(v, 4, 16));
        v = fmaxf(v, __shfl_xor(v, 8, 16));
        rmx[qf][r] = v;
      }
    if (ln16 == 0) {
#pragma unroll
      for (int qf = 0; qf < 2; ++qf)
#pragma unroll
        for (int r = 0; r < 4; ++r) smax[w][qf * 16 + g * 4 + r] = rmx[qf][r];
    }
    __syncthreads();                                   // B1
    float tm = smax[0][j];
#pragma unroll
    for (int wv = 1; wv < NW; ++wv) tm = fmaxf(tm, smax[wv][j]);
    const float mnew = fmaxf(m_run, tm);
    const float alpha = exp2f((m_run - mnew) * LOG2E);
    m_run = mnew;

    float mrow[2][4], arow[2][4];
#pragma unroll
    for (int qf = 0; qf < 2; ++qf)
#pragma unroll
      for (int r = 0; r < 4; ++r) {
        mrow[qf][r] = __shfl(mnew, qf * 16 + g * 4 + r);
        arow[qf][r] = __shfl(alpha, qf * 16 + g * 4 + r);
      }

    float rs[2][4];
#pragma unroll
    for (int qf = 0; qf < 2; ++qf)
#pragma unroll
      for (int r = 0; r < 4; ++r) {
        const float p0 = exp2f((sacc[qf][0][r] - mrow[qf][r]) * LOG2E);
        const float p1 = exp2f((sacc[qf][1][r] - mrow[qf][r]) * LOG2E);
        Ps[qf * 16 + g * 4 + r][w * 32 + ln16]      = f2bf(p0);
        Ps[qf * 16 + g * 4 + r][w * 32 + 16 + ln16] = f2bf(p1);
        float s = p0 + p1;
        s += __shfl_xor(s, 1, 16);
        s += __shfl_xor(s, 2, 16);
        s += __shfl_xor(s, 4, 16);
        s += __shfl_xor(s, 8, 16);
        rs[qf][r] = s;
      }
    if (ln16 == 0) {
#pragma unroll
      for (int qf = 0; qf < 2; ++qf)
#pragma unroll
        for (int r = 0; r < 4; ++r) ssum[w][qf * 16 + g * 4 + r] = rs[qf][r];
    }
    __syncthreads();                                   // B2
    float ts = ssum[0][j];
#pragma unroll
    for (int wv = 1; wv < NW; ++wv) ts += ssum[wv][j];
    l_run = l_run * alpha + ts;

#pragma unroll
    for (int qf = 0; qf < 2; ++qf)
#pragma unroll
      for (int cf = 0; cf < 8; ++cf)
#pragma unroll
        for (int r = 0; r < 4; ++r) oacc[qf][cf][r] *= arow[qf][r];

    // ---- next-tile K ring prologue: issued here so its latency hides under
    // PV MFMAs (arrives during PV; S phase of t+1 starts hot).
    if (t + 1 < NITER) {
      kp0 += (size_t)KVT * DDIM;
      kp1 += (size_t)KVT * DDIM;
#pragma unroll
      for (int p = 0; p < 3; ++p) {
        kb[p][0] = gload16(kp0 + p * 32);
        kb[p][1] = gload16(kp1 + p * 32);
      }
    }

    // ================= O += P V : asm-pinned V ring, no barriers ===========
    const u16* vb = xbfT + (size_t)(w * 128 + ln16) * NROWS + kvb + g * 8;
    int4 vv[2][8];
#pragma unroll
    for (int cf = 0; cf < 8; ++cf)
      vv[0][cf] = gload16(vb + (size_t)(cf * 16) * NROWS);
#pragma unroll
    for (int ks = 0; ks < KS_PV; ++ks) {
      const int cur = ks & 1;
      if (ks + 1 < KS_PV) {
#pragma unroll
        for (int cf = 0; cf < 8; ++cf)
          vv[cur ^ 1][cf] = gload16(vb + (size_t)(cf * 16) * NROWS + (ks + 1) * 32);
      }
      const bf16x8 pa0 = *reinterpret_cast<const bf16x8*>(&Ps[ln16][ks * 32 + g * 8]);
      const bf16x8 pa1 = *reinterpret_cast<const bf16x8*>(&Ps[16 + ln16][ks * 32 + g * 8]);
      // steady-state: 8 (next batch) in flight; tail drains.
      if (ks < KS_PV - 1) VM_WAIT(8);
      else                VM_WAIT(0);
      __builtin_amdgcn_s_setprio(1);
#pragma unroll
      for (int cf = 0; cf < 8; ++cf) {
        oacc[0][cf] = __builtin_amdgcn_mfma_f32_16x16x32_bf16(pa0, asbf(vv[cur][cf]), oacc[0][cf], 0, 0, 0);
        oacc[1][cf] = __builtin_amdgcn_mfma_f32_16x16x32_bf16(pa1, asbf(vv[cur][cf]), oacc[1][cf], 0, 0, 0);
      }
      __builtin_amdgcn_s_setprio(0);
    }
    // No barrier: next S phase touches neither Ps nor stats before B1.
  }

  // ================= epilogue: out = O / l =================================
  const float rinv = 1.0f / l_run;
  float rrow[2][4];
#pragma unroll
  for (int qf = 0; qf < 2; ++qf)
#pragma unroll
    for (int r = 0; r < 4; ++r) rrow[qf][r] = __shfl(rinv, qf * 16 + g * 4 + r);
#pragma unroll
  for (int qf = 0; qf < 2; ++qf)
#pragma unroll
    for (int cf = 0; cf < 8; ++cf)
#pragma unroll
      for (int r = 0; r < 4; ++r) {
        const int row = q0 + qf * 16 + g * 4 + r;
        const int c = w * 128 + cf * 16 + ln16;
        out[(size_t)row * DDIM + c] = oacc[qf][cf][r] * rrow[qf][r];
      }
}

extern "C" void kernel_launch(void* const* d_in, const int* in_sizes, int n_in,
                              void* d_out, int out_size, void* d_ws, size_t ws_size,
                              hipStream_t stream) {
  const float* x = (const float*)d_in[0];
  u16* xbf  = (u16*)d_ws;                        // 16 MB
  u16* xbfT = xbf + (size_t)NROWS * DDIM;        // 16 MB
  float* out = (float*)d_out;

  hipLaunchKernelGGL(prep_kernel, dim3(NROWS / 64, DDIM / 64), dim3(256), 0, stream,
                     x, xbf, xbfT);
  hipLaunchKernelGGL(attn_kernel, dim3(NROWS / QBLK), dim3(512), 0, stream,
                     xbf, xbfT, out);
}